// Round 3
// baseline (312.148 us; speedup 1.0000x reference)
//
#include <hip/hip_runtime.h>

#define B_ 256
#define K_ 10
#define I_ 1152
#define O_ 16
#define C_ 8

static __device__ __forceinline__ unsigned short f32_bf16(float f) {
    unsigned int u = __float_as_uint(f);
    u += 0x7FFFu + ((u >> 16) & 1u);           // round-to-nearest-even
    return (unsigned short)(u >> 16);
}

// unpack uint2 (4 packed bf16) -> 4 floats
#define UNPACK4(P, F0, F1, F2, F3)                         \
    {                                                      \
        F0 = __uint_as_float((P).x << 16);                 \
        F1 = __uint_as_float((P).x & 0xffff0000u);         \
        F2 = __uint_as_float((P).y << 16);                 \
        F3 = __uint_as_float((P).y & 0xffff0000u);         \
    }

// ---------------------------------------------------------------------------
// uhat_kernel v2: u[b][k][i][o] = bf16( sum_c w[k,i,o,c] * x[b,i,c] )
// grid (72, 4, 2): i0 = x*16, b0 = y*64, k-half = z.  256 thr: i_l=t&15,
// bg=t>>4; each thread computes 4 consecutive b (b0+bg*4+bb) for its i and
// all 16 o -> LDS w reads amortized 4x vs round-2 (755 -> 189 MB).
// ---------------------------------------------------------------------------
__global__ __launch_bounds__(256, 2) void uhat_kernel(
    const float* __restrict__ x, const float* __restrict__ w,
    unsigned short* __restrict__ u)
{
    __shared__ float w_lds[16 * 132];   // [ii][o*8+c], stride 132 -> 2-way max (free)
    const int t     = threadIdx.x;
    const int i_l   = t & 15, bg = t >> 4;
    const int i0    = blockIdx.x * 16;
    const int b0    = blockIdx.y * 64 + bg * 4;
    const int kbase = blockIdx.z * 5;
    const int i     = i0 + i_l;

    float4 xr[4][2];
#pragma unroll
    for (int bb = 0; bb < 4; bb++) {
        const float4* xp = (const float4*)(x + ((size_t)(b0 + bb) * I_ + i) * C_);
        xr[bb][0] = xp[0];
        xr[bb][1] = xp[1];
    }

    for (int kk = 0; kk < 5; kk++) {
        const int k = kbase + kk;
        __syncthreads();
        const float4* ws = (const float4*)(w + ((size_t)k * I_ + i0) * O_ * C_);
#pragma unroll
        for (int r = 0; r < 2; r++) {
            int idx = r * 256 + t;               // float4 index in 16x128 slab
            int ii = idx >> 5, rem = idx & 31;
            *(float4*)&w_lds[ii * 132 + rem * 4] = ws[idx];
        }
        __syncthreads();

        unsigned int pk[4][8];
#pragma unroll
        for (int oo = 0; oo < 8; oo++) {
            float d[4][2];
#pragma unroll
            for (int h = 0; h < 2; h++) {
                const int o = oo * 2 + h;
                const float4 w0 = *(const float4*)&w_lds[i_l * 132 + o * 8];
                const float4 w1 = *(const float4*)&w_lds[i_l * 132 + o * 8 + 4];
#pragma unroll
                for (int bb = 0; bb < 4; bb++) {
                    d[bb][h] = w0.x*xr[bb][0].x + w0.y*xr[bb][0].y
                             + w0.z*xr[bb][0].z + w0.w*xr[bb][0].w
                             + w1.x*xr[bb][1].x + w1.y*xr[bb][1].y
                             + w1.z*xr[bb][1].z + w1.w*xr[bb][1].w;
                }
            }
#pragma unroll
            for (int bb = 0; bb < 4; bb++)
                pk[bb][oo] = (unsigned int)f32_bf16(d[bb][0]) |
                             ((unsigned int)f32_bf16(d[bb][1]) << 16);
        }
#pragma unroll
        for (int bb = 0; bb < 4; bb++) {
            unsigned int* dst = (unsigned int*)
                (u + (((size_t)(b0 + bb) * K_ + k) * I_ + i) * O_);
            *(uint4*)(dst)     = make_uint4(pk[bb][0], pk[bb][1], pk[bb][2], pk[bb][3]);
            *(uint4*)(dst + 4) = make_uint4(pk[bb][4], pk[bb][5], pk[bb][6], pk[bb][7]);
        }
    }
}

// ---------------------------------------------------------------------------
// route_fused: ALL routing passes + squashes for one b in one block.
// u[b] (10x1152x16 bf16 = 368 KB) loaded once into registers:
//   thread (og=t&3, i_l=t>>2): U[ii][k] = u[b,k, ii*192+i_l, og*4..og*4+3]
// pass1: s = (1/K) sum_i u  -> squash -> v1 (LDS)
// pass p=2,3: logits l[k,i]=sum_o u*v (2 og-shuffles), softmax over k,
//   c cached packed-bf16 in regs; s = sum_i c*u -> squash.
// v-telescope: pass3 uses v1+v2. Final v written straight to d_out.
// ---------------------------------------------------------------------------
__global__ __launch_bounds__(768, 3) void route_fused(
    const unsigned short* __restrict__ u, float* __restrict__ out)
{
    __shared__ float red[12 * 160];
    __shared__ float vbuf[160];     // v of previous pass
    __shared__ float vacc[160];     // v1+v2
    const int t    = threadIdx.x;
    const int og   = t & 3, i_l = t >> 2;     // i_l in 0..191
    const int b    = blockIdx.x;
    const int lane = t & 63, wv = t >> 6;

    // ---- load phase: 60 x 8B coalesced (512 B per wave-inst) ----
    uint2 U[6][10];
    const unsigned short* ub = u + (size_t)b * K_ * I_ * O_ + og * 4;
#pragma unroll
    for (int ii = 0; ii < 6; ii++)
#pragma unroll
        for (int k = 0; k < 10; k++)
            U[ii][k] = *(const uint2*)(ub + ((size_t)k * I_ + ii * 192 + i_l) * O_);

    // ---- pass 1: uniform c = 1/K ----
#pragma unroll
    for (int k = 0; k < 10; k++) {
        float a0 = 0.f, a1 = 0.f, a2 = 0.f, a3 = 0.f;
#pragma unroll
        for (int ii = 0; ii < 6; ii++) {
            float f0, f1, f2, f3;
            UNPACK4(U[ii][k], f0, f1, f2, f3);
            a0 += f0; a1 += f1; a2 += f2; a3 += f3;
        }
#pragma unroll
        for (int s = 4; s < 64; s <<= 1) {
            a0 += __shfl_xor(a0, s); a1 += __shfl_xor(a1, s);
            a2 += __shfl_xor(a2, s); a3 += __shfl_xor(a3, s);
        }
        if (lane < 4)
            *(float4*)&red[wv * 160 + k * 16 + lane * 4] = make_float4(a0, a1, a2, a3);
    }
    __syncthreads();
    if (t < 160) {
        float s = 0.f;
#pragma unroll
        for (int wgi = 0; wgi < 12; wgi++) s += red[wgi * 160 + t];
        s *= (1.0f / K_);
        float n2 = s * s;
        n2 += __shfl_xor(n2, 1); n2 += __shfl_xor(n2, 2);
        n2 += __shfl_xor(n2, 4); n2 += __shfl_xor(n2, 8);
        const float norm = sqrtf(n2);
        const float sc   = n2 / (1.0f + n2) / (norm + 1e-9f);
        const float v    = sc * s;
        vbuf[t] = v;
        vacc[t] = v;
    }
    __syncthreads();

    // ---- passes 2 and 3 ----
#pragma unroll 1
    for (int p = 0; p < 2; p++) {
        const float* vin = (p == 0) ? vbuf : vacc;

        // sweep A: logits -> softmax -> packed bf16 c
        unsigned int Cp[6][5];
#pragma unroll
        for (int ii = 0; ii < 6; ii++) {
            float l[10];
#pragma unroll
            for (int k = 0; k < 10; k++) {
                float f0, f1, f2, f3;
                UNPACK4(U[ii][k], f0, f1, f2, f3);
                const float* vk = vin + k * 16 + og * 4;
                float lk = f0 * vk[0] + f1 * vk[1] + f2 * vk[2] + f3 * vk[3];
                lk += __shfl_xor(lk, 1);
                lk += __shfl_xor(lk, 2);
                l[k] = lk;
            }
            float m = l[0];
#pragma unroll
            for (int k = 1; k < 10; k++) m = fmaxf(m, l[k]);
            float Z = 0.f;
#pragma unroll
            for (int k = 0; k < 10; k++) { l[k] = __expf(l[k] - m); Z += l[k]; }
            const float inv = 1.0f / Z;
#pragma unroll
            for (int kk = 0; kk < 5; kk++)
                Cp[ii][kk] = (unsigned int)f32_bf16(l[2 * kk] * inv) |
                             ((unsigned int)f32_bf16(l[2 * kk + 1] * inv) << 16);
        }

        // sweep B: s[k] = sum_i c * u
#pragma unroll
        for (int k = 0; k < 10; k++) {
            float a0 = 0.f, a1 = 0.f, a2 = 0.f, a3 = 0.f;
#pragma unroll
            for (int ii = 0; ii < 6; ii++) {
                const unsigned int cp = Cp[ii][k >> 1];
                const float c = __uint_as_float((k & 1) ? (cp & 0xffff0000u)
                                                        : (cp << 16));
                float f0, f1, f2, f3;
                UNPACK4(U[ii][k], f0, f1, f2, f3);
                a0 = fmaf(c, f0, a0); a1 = fmaf(c, f1, a1);
                a2 = fmaf(c, f2, a2); a3 = fmaf(c, f3, a3);
            }
#pragma unroll
            for (int s = 4; s < 64; s <<= 1) {
                a0 += __shfl_xor(a0, s); a1 += __shfl_xor(a1, s);
                a2 += __shfl_xor(a2, s); a3 += __shfl_xor(a3, s);
            }
            if (lane < 4)
                *(float4*)&red[wv * 160 + k * 16 + lane * 4] = make_float4(a0, a1, a2, a3);
        }
        __syncthreads();
        if (t < 160) {
            float s = 0.f;
#pragma unroll
            for (int wgi = 0; wgi < 12; wgi++) s += red[wgi * 160 + t];
            float n2 = s * s;
            n2 += __shfl_xor(n2, 1); n2 += __shfl_xor(n2, 2);
            n2 += __shfl_xor(n2, 4); n2 += __shfl_xor(n2, 8);
            const float norm = sqrtf(n2);
            const float sc   = n2 / (1.0f + n2) / (norm + 1e-9f);
            const float v    = sc * s;
            if (p == 0) { vbuf[t] = v; vacc[t] += v; }   // vacc = v1+v2
            else        out[(size_t)b * 160 + t] = v;
        }
        __syncthreads();
    }
}

// ---------------------------------------------------------------------------
extern "C" void kernel_launch(void* const* d_in, const int* in_sizes, int n_in,
                              void* d_out, int out_size, void* d_ws, size_t ws_size,
                              hipStream_t stream)
{
    const float* x = (const float*)d_in[0];
    const float* w = (const float*)d_in[1];
    float* outp = (float*)d_out;

    unsigned short* u = (unsigned short*)d_ws;   // B*K*I*O bf16 = 92 MB

    uhat_kernel<<<dim3(72, 4, 2), 256, 0, stream>>>(x, w, u);
    route_fused<<<256, 768, 0, stream>>>(u, outp);
}

// Round 4
// 183.784 us; speedup vs baseline: 1.6984x; 1.6984x over previous
//
#include <hip/hip_runtime.h>

#define B_ 256
#define K_ 10
#define I_ 1152
#define O_ 16
#define C_ 8
#define BKO (B_*K_*O_)   // 40960

static __device__ __forceinline__ unsigned short f32_bf16(float f) {
    unsigned int u = __float_as_uint(f);
    u += 0x7FFFu + ((u >> 16) & 1u);           // round-to-nearest-even
    return (unsigned short)(u >> 16);
}

// unpack uint2 (4 packed bf16) -> 4 floats
#define UNPACK4(P, F0, F1, F2, F3)                         \
    {                                                      \
        F0 = __uint_as_float((P).x << 16);                 \
        F1 = __uint_as_float((P).x & 0xffff0000u);         \
        F2 = __uint_as_float((P).y << 16);                 \
        F3 = __uint_as_float((P).y & 0xffff0000u);         \
    }

// ---------------------------------------------------------------------------
// uhat_kernel: u[b][k][i][o] = bf16( sum_c w[k,i,o,c] * x[b,i,c] )
// grid (72, 16, 2): i0 = x*16, b0 = y*16, k-half = z (5 k each).
// 256 thr: i_l = t&15, b_l = t>>4.  2304 blocks -> ~8 waves/SIMD (round-2's
// 1152-block version sat at 36% occupancy; k-split doubles parallelism for
// +9.4 MB x re-read and +6 MB w re-read, both trivial).
// ---------------------------------------------------------------------------
__global__ __launch_bounds__(256) void uhat_kernel(
    const float* __restrict__ x, const float* __restrict__ w,
    unsigned short* __restrict__ u)
{
    __shared__ float w_lds[16 * 132];   // [ii][o*8+c], stride 132: 2-way max (free)
    const int t   = threadIdx.x;
    const int i_l = t & 15, b_l = t >> 4;
    const int i0  = blockIdx.x * 16;
    const int b   = blockIdx.y * 16 + b_l;
    const int kb  = blockIdx.z * 5;
    const int i   = i0 + i_l;

    const float4* xp = (const float4*)(x + ((size_t)b * I_ + i) * C_);
    const float4 x0 = xp[0], x1 = xp[1];

    for (int kk = 0; kk < 5; kk++) {
        const int k = kb + kk;
        __syncthreads();
        const float4* ws = (const float4*)(w + ((size_t)k * I_ + i0) * O_ * C_);
#pragma unroll
        for (int r = 0; r < 2; r++) {
            int idx = r * 256 + t;               // float4 index in 16x128 slab
            int ii = idx >> 5, rem = idx & 31;
            *(float4*)&w_lds[ii * 132 + rem * 4] = ws[idx];
        }
        __syncthreads();

        unsigned int pk[8];
#pragma unroll
        for (int oo = 0; oo < 8; oo++) {
            float uo2[2];
#pragma unroll
            for (int h = 0; h < 2; h++) {
                const int o = oo * 2 + h;
                const float4 w0 = *(const float4*)&w_lds[i_l * 132 + o * 8];
                const float4 w1 = *(const float4*)&w_lds[i_l * 132 + o * 8 + 4];
                uo2[h] = w0.x*x0.x + w0.y*x0.y + w0.z*x0.z + w0.w*x0.w
                       + w1.x*x1.x + w1.y*x1.y + w1.z*x1.z + w1.w*x1.w;
            }
            pk[oo] = (unsigned int)f32_bf16(uo2[0]) |
                     ((unsigned int)f32_bf16(uo2[1]) << 16);
        }
        unsigned int* dst = (unsigned int*)(u + (((size_t)b * K_ + k) * I_ + i) * O_);
        *(uint4*)(dst)     = make_uint4(pk[0], pk[1], pk[2], pk[3]);
        *(uint4*)(dst + 4) = make_uint4(pk[4], pk[5], pk[6], pk[7]);
    }
}

// ---------------------------------------------------------------------------
// route_uniform: pass 1 only.  s_part[p][b][k][o] = (1/K) sum_{i in part} u.
// Pure streaming reduce: no logits/softmax.  grid (NP, 256), 256 thr.
// thread: og = t&3 (o-quad), i_l = t>>2 (0..63).
// ---------------------------------------------------------------------------
template <int NP>
__global__ __launch_bounds__(256) void route_uniform(
    const unsigned short* __restrict__ u, float* __restrict__ s_part)
{
    constexpr int NIC = I_ / (64 * NP);
    __shared__ float red[4 * 160];
    const int t  = threadIdx.x;
    const int og = t & 3, i_l = t >> 2;
    const int p  = blockIdx.x, b = blockIdx.y;
    const int lane = t & 63, wv = t >> 6;

    const unsigned short* ub = u + (size_t)b * K_ * I_ * O_ + og * 4;

    float acc[K_][4];
#pragma unroll
    for (int k = 0; k < K_; k++)
#pragma unroll
        for (int j = 0; j < 4; j++) acc[k][j] = 0.f;

    uint2 P[K_], Q[K_];
#pragma unroll
    for (int k = 0; k < K_; k++)
        P[k] = *(const uint2*)(ub + ((size_t)k * I_ + p * 64 * NIC + i_l) * O_);

#pragma unroll
    for (int ic = 0; ic < NIC; ic++) {
        if (ic + 1 < NIC) {
            const int i = p * 64 * NIC + (ic + 1) * 64 + i_l;
#pragma unroll
            for (int k = 0; k < K_; k++)
                Q[k] = *(const uint2*)(ub + ((size_t)k * I_ + i) * O_);
        }
#pragma unroll
        for (int k = 0; k < K_; k++) {
            float f0, f1, f2, f3;
            UNPACK4(P[k], f0, f1, f2, f3);
            acc[k][0] += f0; acc[k][1] += f1; acc[k][2] += f2; acc[k][3] += f3;
        }
#pragma unroll
        for (int k = 0; k < K_; k++) P[k] = Q[k];
    }

#pragma unroll
    for (int k = 0; k < K_; k++)
#pragma unroll
        for (int j = 0; j < 4; j++) {
            float a = acc[k][j];
            a += __shfl_xor(a, 4);  a += __shfl_xor(a, 8);
            a += __shfl_xor(a, 16); a += __shfl_xor(a, 32);
            acc[k][j] = a;
        }
    if (lane < 4) {
#pragma unroll
        for (int k = 0; k < K_; k++)
            *(float4*)&red[wv * 160 + k * 16 + lane * 4] =
                make_float4(acc[k][0], acc[k][1], acc[k][2], acc[k][3]);
    }
    __syncthreads();
    if (t < 160) {
        float s = (red[t] + red[160 + t] + red[320 + t] + red[480 + t]) * (1.0f / K_);
        s_part[(size_t)p * BKO + (size_t)b * 160 + t] = s;
    }
}

// ---------------------------------------------------------------------------
// route_pass: logits -> softmax_k -> weighted sum, one i-partition per block.
// grid (NP, 256), 256 thr: og = t&3, i_l = t>>2.
// Loads stay packed in regs (P/Q double-buffer); unpack twice (cheap) to keep
// VGPR ~100 (no spill -- round-3's lesson).
// ---------------------------------------------------------------------------
template <int NP>
__global__ __launch_bounds__(256) void route_pass(
    const unsigned short* __restrict__ u, const float* __restrict__ v,
    float* __restrict__ s_part)
{
    constexpr int NIC = I_ / (64 * NP);
    __shared__ float v_lds[160];
    __shared__ float red[4 * 160];
    const int t  = threadIdx.x;
    const int og = t & 3, i_l = t >> 2;
    const int p  = blockIdx.x, b = blockIdx.y;
    const int lane = t & 63, wv = t >> 6;

    if (t < 160) v_lds[t] = v[(size_t)b * 160 + t];

    const unsigned short* ub = u + (size_t)b * K_ * I_ * O_ + og * 4;

    float acc[K_][4];
#pragma unroll
    for (int k = 0; k < K_; k++)
#pragma unroll
        for (int j = 0; j < 4; j++) acc[k][j] = 0.f;

    uint2 P[K_], Q[K_];
#pragma unroll
    for (int k = 0; k < K_; k++)
        P[k] = *(const uint2*)(ub + ((size_t)k * I_ + p * 64 * NIC + i_l) * O_);

    __syncthreads();   // v_lds ready

#pragma unroll
    for (int ic = 0; ic < NIC; ic++) {
        if (ic + 1 < NIC) {
            const int i = p * 64 * NIC + (ic + 1) * 64 + i_l;
#pragma unroll
            for (int k = 0; k < K_; k++)
                Q[k] = *(const uint2*)(ub + ((size_t)k * I_ + i) * O_);
        }
        // logits
        float l[K_];
#pragma unroll
        for (int k = 0; k < K_; k++) {
            float f0, f1, f2, f3;
            UNPACK4(P[k], f0, f1, f2, f3);
            const float* vk = &v_lds[k * 16 + og * 4];
            float lk = f0 * vk[0] + f1 * vk[1] + f2 * vk[2] + f3 * vk[3];
            lk += __shfl_xor(lk, 1);
            lk += __shfl_xor(lk, 2);
            l[k] = lk;
        }
        // softmax over k
        float m = l[0];
#pragma unroll
        for (int k = 1; k < K_; k++) m = fmaxf(m, l[k]);
        float Z = 0.f;
#pragma unroll
        for (int k = 0; k < K_; k++) { l[k] = __expf(l[k] - m); Z += l[k]; }
        const float inv = 1.0f / Z;
        // accumulate
#pragma unroll
        for (int k = 0; k < K_; k++) {
            const float c = l[k] * inv;
            float f0, f1, f2, f3;
            UNPACK4(P[k], f0, f1, f2, f3);
            acc[k][0] = fmaf(c, f0, acc[k][0]);
            acc[k][1] = fmaf(c, f1, acc[k][1]);
            acc[k][2] = fmaf(c, f2, acc[k][2]);
            acc[k][3] = fmaf(c, f3, acc[k][3]);
        }
#pragma unroll
        for (int k = 0; k < K_; k++) P[k] = Q[k];
    }

#pragma unroll
    for (int k = 0; k < K_; k++)
#pragma unroll
        for (int j = 0; j < 4; j++) {
            float a = acc[k][j];
            a += __shfl_xor(a, 4);  a += __shfl_xor(a, 8);
            a += __shfl_xor(a, 16); a += __shfl_xor(a, 32);
            acc[k][j] = a;
        }
    if (lane < 4) {
#pragma unroll
        for (int k = 0; k < K_; k++)
            *(float4*)&red[wv * 160 + k * 16 + lane * 4] =
                make_float4(acc[k][0], acc[k][1], acc[k][2], acc[k][3]);
    }
    __syncthreads();
    if (t < 160) {
        float s = red[t] + red[160 + t] + red[320 + t] + red[480 + t];
        s_part[(size_t)p * BKO + (size_t)b * 160 + t] = s;
    }
}

// ---------------------------------------------------------------------------
// squash_kernel: s = sum of NP partials; v = squash(s)
// mode 0: v_out=v, vacc=v | mode 1: v_out=v, vacc+=v | mode 2: v_out=v only
// ---------------------------------------------------------------------------
template <int NP>
__global__ __launch_bounds__(256) void squash_kernel(
    const float* __restrict__ s_part, float* __restrict__ v_out,
    float* __restrict__ vacc, int mode)
{
    const int g = blockIdx.x * 256 + threadIdx.x;   // [b][k][o] linear
    float sv = 0.f;
#pragma unroll
    for (int p = 0; p < NP; p++) sv += s_part[(size_t)p * BKO + g];
    float n2 = sv * sv;
    n2 += __shfl_xor(n2, 1);
    n2 += __shfl_xor(n2, 2);
    n2 += __shfl_xor(n2, 4);
    n2 += __shfl_xor(n2, 8);
    const float norm  = sqrtf(n2);
    const float scale = n2 / (1.0f + n2) / (norm + 1e-9f);
    const float vv = scale * sv;
    v_out[g] = vv;
    if (mode == 0)      vacc[g] = vv;
    else if (mode == 1) vacc[g] = vacc[g] + vv;
}

// ---------------------------------------------------------------------------
template <int NP>
static void run_pipeline(const float* x, const float* w, float* outp,
                         void* d_ws, hipStream_t stream)
{
    float* s_buf = (float*)d_ws;                       // NP*BKO
    float* v_buf = s_buf + (size_t)NP * BKO;           // BKO
    float* vacc  = v_buf + BKO;                        // BKO
    unsigned short* u = (unsigned short*)(vacc + BKO); // B*K*I*O bf16

    uhat_kernel<<<dim3(72, 16, 2), 256, 0, stream>>>(x, w, u);
    // pass 1 (uniform c = 1/K)
    route_uniform<NP><<<dim3(NP, 256), 256, 0, stream>>>(u, s_buf);
    squash_kernel<NP><<<160, 256, 0, stream>>>(s_buf, v_buf, vacc, 0);
    // pass 2: b-logits from v1
    route_pass<NP><<<dim3(NP, 256), 256, 0, stream>>>(u, v_buf, s_buf);
    squash_kernel<NP><<<160, 256, 0, stream>>>(s_buf, v_buf, vacc, 1);
    // pass 3 (final): logits from v1+v2 (telescoped)
    route_pass<NP><<<dim3(NP, 256), 256, 0, stream>>>(u, vacc, s_buf);
    squash_kernel<NP><<<160, 256, 0, stream>>>(s_buf, outp, nullptr, 2);
}

extern "C" void kernel_launch(void* const* d_in, const int* in_sizes, int n_in,
                              void* d_out, int out_size, void* d_ws, size_t ws_size,
                              hipStream_t stream)
{
    const float* x = (const float*)d_in[0];
    const float* w = (const float*)d_in[1];
    float* outp = (float*)d_out;

    const size_t ubytes = (size_t)B_ * K_ * I_ * O_ * 2;
    if (ws_size >= (size_t)(9 + 2) * BKO * 4 + ubytes)
        run_pipeline<9>(x, w, outp, d_ws, stream);
    else
        run_pipeline<3>(x, w, outp, d_ws, stream);
}

// Round 5
// 165.891 us; speedup vs baseline: 1.8816x; 1.1079x over previous
//
#include <hip/hip_runtime.h>

#define B_ 256
#define K_ 10
#define I_ 1152
#define O_ 16
#define C_ 8
#define BKO (B_*K_*O_)   // 40960

static __device__ __forceinline__ unsigned short f32_bf16(float f) {
    unsigned int u = __float_as_uint(f);
    u += 0x7FFFu + ((u >> 16) & 1u);           // round-to-nearest-even
    return (unsigned short)(u >> 16);
}

// unpack uint2 (4 packed bf16) -> 4 floats
#define UNPACK4(P, F0, F1, F2, F3)                         \
    {                                                      \
        F0 = __uint_as_float((P).x << 16);                 \
        F1 = __uint_as_float((P).x & 0xffff0000u);         \
        F2 = __uint_as_float((P).y << 16);                 \
        F3 = __uint_as_float((P).y & 0xffff0000u);         \
    }

// ---------------------------------------------------------------------------
// uhat_kernel v3: u[b][k][i][o] = bf16( sum_c w[k,i,o,c] * x[b,i,c] )
// grid (72, 4, 5): i0 = x*16, b0 = y*64, kb = z*2 (2 k's per block).
// 256 thr: i_l = t&15, tg = t>>4; each thread computes 4 b's (b0+tg*4+bb).
// Each ds_read_b128 of a w row now feeds 4 b's of FMAs -> LDS pipe time /4
// vs round-4 (which was LDS-bound at ~40 of its 50 us).
// ---------------------------------------------------------------------------
__global__ __launch_bounds__(256) void uhat_kernel(
    const float* __restrict__ x, const float* __restrict__ w,
    unsigned short* __restrict__ u)
{
    __shared__ float w_lds[16 * 132];   // [ii][o*8+c], stride 132: 2-way max
    const int t   = threadIdx.x;
    const int i_l = t & 15, tg = t >> 4;
    const int i0  = blockIdx.x * 16;
    const int b0  = blockIdx.y * 64 + tg * 4;
    const int kb  = blockIdx.z * 2;
    const int i   = i0 + i_l;

    float4 xr[4][2];
#pragma unroll
    for (int bb = 0; bb < 4; bb++) {
        const float4* xp = (const float4*)(x + ((size_t)(b0 + bb) * I_ + i) * C_);
        xr[bb][0] = xp[0];
        xr[bb][1] = xp[1];
    }

#pragma unroll
    for (int kk = 0; kk < 2; kk++) {
        const int k = kb + kk;
        __syncthreads();
        const float4* ws = (const float4*)(w + ((size_t)k * I_ + i0) * O_ * C_);
#pragma unroll
        for (int r = 0; r < 2; r++) {
            int idx = r * 256 + t;               // float4 index in 16x128 slab
            int ii = idx >> 5, rem = idx & 31;
            *(float4*)&w_lds[ii * 132 + rem * 4] = ws[idx];
        }
        __syncthreads();

#pragma unroll
        for (int half = 0; half < 2; half++) {   // o 0..7 then 8..15
            unsigned int pk[4][4];
#pragma unroll
            for (int oq = 0; oq < 4; oq++) {
                const int oo = half * 4 + oq;    // o-pair index
                float d[4][2];
#pragma unroll
                for (int h = 0; h < 2; h++) {
                    const int o = oo * 2 + h;
                    const float4 w0 = *(const float4*)&w_lds[i_l * 132 + o * 8];
                    const float4 w1 = *(const float4*)&w_lds[i_l * 132 + o * 8 + 4];
#pragma unroll
                    for (int bb = 0; bb < 4; bb++) {
                        d[bb][h] = w0.x*xr[bb][0].x + w0.y*xr[bb][0].y
                                 + w0.z*xr[bb][0].z + w0.w*xr[bb][0].w
                                 + w1.x*xr[bb][1].x + w1.y*xr[bb][1].y
                                 + w1.z*xr[bb][1].z + w1.w*xr[bb][1].w;
                    }
                }
#pragma unroll
                for (int bb = 0; bb < 4; bb++)
                    pk[bb][oq] = (unsigned int)f32_bf16(d[bb][0]) |
                                 ((unsigned int)f32_bf16(d[bb][1]) << 16);
            }
#pragma unroll
            for (int bb = 0; bb < 4; bb++) {
                unsigned int* dst = (unsigned int*)
                    (u + (((size_t)(b0 + bb) * K_ + k) * I_ + i) * O_) + half * 4;
                *(uint4*)dst = make_uint4(pk[bb][0], pk[bb][1], pk[bb][2], pk[bb][3]);
            }
        }
    }
}

// ---------------------------------------------------------------------------
// route_uniform: pass 1.  s_part[p][b][k][o] = (1/K) sum_{i in part} u.
// grid (NP, 256), 256 thr: og = t&3 (o-quad), i_l = t>>2.
// ---------------------------------------------------------------------------
template <int NP>
__global__ __launch_bounds__(256) void route_uniform(
    const unsigned short* __restrict__ u, float* __restrict__ s_part)
{
    constexpr int NIC = I_ / (64 * NP);
    __shared__ float red[4 * 160];
    const int t  = threadIdx.x;
    const int og = t & 3, i_l = t >> 2;
    const int p  = blockIdx.x, b = blockIdx.y;
    const int lane = t & 63, wv = t >> 6;

    const unsigned short* ub = u + (size_t)b * K_ * I_ * O_ + og * 4;

    float acc[K_][4];
#pragma unroll
    for (int k = 0; k < K_; k++)
#pragma unroll
        for (int j = 0; j < 4; j++) acc[k][j] = 0.f;

    uint2 P[K_], Q[K_];
#pragma unroll
    for (int k = 0; k < K_; k++)
        P[k] = *(const uint2*)(ub + ((size_t)k * I_ + p * 64 * NIC + i_l) * O_);

#pragma unroll
    for (int ic = 0; ic < NIC; ic++) {
        if (ic + 1 < NIC) {
            const int i = p * 64 * NIC + (ic + 1) * 64 + i_l;
#pragma unroll
            for (int k = 0; k < K_; k++)
                Q[k] = *(const uint2*)(ub + ((size_t)k * I_ + i) * O_);
        }
#pragma unroll
        for (int k = 0; k < K_; k++) {
            float f0, f1, f2, f3;
            UNPACK4(P[k], f0, f1, f2, f3);
            acc[k][0] += f0; acc[k][1] += f1; acc[k][2] += f2; acc[k][3] += f3;
        }
#pragma unroll
        for (int k = 0; k < K_; k++) P[k] = Q[k];
    }

#pragma unroll
    for (int k = 0; k < K_; k++)
#pragma unroll
        for (int j = 0; j < 4; j++) {
            float a = acc[k][j];
            a += __shfl_xor(a, 4);  a += __shfl_xor(a, 8);
            a += __shfl_xor(a, 16); a += __shfl_xor(a, 32);
            acc[k][j] = a;
        }
    if (lane < 4) {
#pragma unroll
        for (int k = 0; k < K_; k++)
            *(float4*)&red[wv * 160 + k * 16 + lane * 4] =
                make_float4(acc[k][0], acc[k][1], acc[k][2], acc[k][3]);
    }
    __syncthreads();
    if (t < 160) {
        float s = (red[t] + red[160 + t] + red[320 + t] + red[480 + t]) * (1.0f / K_);
        s_part[(size_t)p * BKO + (size_t)b * 160 + t] = s;
    }
}

// ---------------------------------------------------------------------------
// route_pass: fused squash-prologue + routing pass.
//   prologue (160 thr): v = squash(sum_p sIn[p][b]);
//     if ADD_V1: v += v1buf[b]  (telescoped v1+v2 for pass 3)
//     if WRITE_V1 && p==0: v1buf[b] = v
//   body: logits -> softmax_k -> weighted sum over the block's i-partition.
// ---------------------------------------------------------------------------
template <int NP, int ADD_V1, int WRITE_V1>
__global__ __launch_bounds__(256) void route_pass(
    const unsigned short* __restrict__ u, const float* __restrict__ sIn,
    float* __restrict__ v1buf, float* __restrict__ sOut)
{
    constexpr int NIC = I_ / (64 * NP);
    __shared__ float v_lds[160];
    __shared__ float red[4 * 160];
    const int t  = threadIdx.x;
    const int og = t & 3, i_l = t >> 2;
    const int p  = blockIdx.x, b = blockIdx.y;
    const int lane = t & 63, wv = t >> 6;

    // ---- squash prologue ----
    if (t < 160) {
        float s = 0.f;
#pragma unroll
        for (int q = 0; q < NP; q++) s += sIn[(size_t)q * BKO + (size_t)b * 160 + t];
        float n2 = s * s;
        n2 += __shfl_xor(n2, 1); n2 += __shfl_xor(n2, 2);
        n2 += __shfl_xor(n2, 4); n2 += __shfl_xor(n2, 8);
        const float norm = sqrtf(n2);
        const float sc   = n2 / (1.0f + n2) / (norm + 1e-9f);
        float v = sc * s;
        if (ADD_V1) v += v1buf[(size_t)b * 160 + t];
        if (WRITE_V1 && p == 0) v1buf[(size_t)b * 160 + t] = v;
        v_lds[t] = v;
    }

    const unsigned short* ub = u + (size_t)b * K_ * I_ * O_ + og * 4;

    float acc[K_][4];
#pragma unroll
    for (int k = 0; k < K_; k++)
#pragma unroll
        for (int j = 0; j < 4; j++) acc[k][j] = 0.f;

    uint2 P[K_], Q[K_];
#pragma unroll
    for (int k = 0; k < K_; k++)
        P[k] = *(const uint2*)(ub + ((size_t)k * I_ + p * 64 * NIC + i_l) * O_);

    __syncthreads();   // v_lds ready

#pragma unroll
    for (int ic = 0; ic < NIC; ic++) {
        if (ic + 1 < NIC) {
            const int i = p * 64 * NIC + (ic + 1) * 64 + i_l;
#pragma unroll
            for (int k = 0; k < K_; k++)
                Q[k] = *(const uint2*)(ub + ((size_t)k * I_ + i) * O_);
        }
        // logits
        float l[K_];
#pragma unroll
        for (int k = 0; k < K_; k++) {
            float f0, f1, f2, f3;
            UNPACK4(P[k], f0, f1, f2, f3);
            const float* vk = &v_lds[k * 16 + og * 4];
            float lk = f0 * vk[0] + f1 * vk[1] + f2 * vk[2] + f3 * vk[3];
            lk += __shfl_xor(lk, 1);
            lk += __shfl_xor(lk, 2);
            l[k] = lk;
        }
        // softmax over k
        float m = l[0];
#pragma unroll
        for (int k = 1; k < K_; k++) m = fmaxf(m, l[k]);
        float Z = 0.f;
#pragma unroll
        for (int k = 0; k < K_; k++) { l[k] = __expf(l[k] - m); Z += l[k]; }
        const float inv = 1.0f / Z;
        // accumulate
#pragma unroll
        for (int k = 0; k < K_; k++) {
            const float c = l[k] * inv;
            float f0, f1, f2, f3;
            UNPACK4(P[k], f0, f1, f2, f3);
            acc[k][0] = fmaf(c, f0, acc[k][0]);
            acc[k][1] = fmaf(c, f1, acc[k][1]);
            acc[k][2] = fmaf(c, f2, acc[k][2]);
            acc[k][3] = fmaf(c, f3, acc[k][3]);
        }
#pragma unroll
        for (int k = 0; k < K_; k++) P[k] = Q[k];
    }

#pragma unroll
    for (int k = 0; k < K_; k++)
#pragma unroll
        for (int j = 0; j < 4; j++) {
            float a = acc[k][j];
            a += __shfl_xor(a, 4);  a += __shfl_xor(a, 8);
            a += __shfl_xor(a, 16); a += __shfl_xor(a, 32);
            acc[k][j] = a;
        }
    if (lane < 4) {
#pragma unroll
        for (int k = 0; k < K_; k++)
            *(float4*)&red[wv * 160 + k * 16 + lane * 4] =
                make_float4(acc[k][0], acc[k][1], acc[k][2], acc[k][3]);
    }
    __syncthreads();
    if (t < 160) {
        float s = red[t] + red[160 + t] + red[320 + t] + red[480 + t];
        sOut[(size_t)p * BKO + (size_t)b * 160 + t] = s;
    }
}

// ---------------------------------------------------------------------------
// squash_final: out = squash(sum_p s_part)
// ---------------------------------------------------------------------------
template <int NP>
__global__ __launch_bounds__(256) void squash_final(
    const float* __restrict__ s_part, float* __restrict__ out)
{
    const int g = blockIdx.x * 256 + threadIdx.x;   // [b][k][o] linear
    float sv = 0.f;
#pragma unroll
    for (int p = 0; p < NP; p++) sv += s_part[(size_t)p * BKO + g];
    float n2 = sv * sv;
    n2 += __shfl_xor(n2, 1);
    n2 += __shfl_xor(n2, 2);
    n2 += __shfl_xor(n2, 4);
    n2 += __shfl_xor(n2, 8);
    const float norm  = sqrtf(n2);
    const float scale = n2 / (1.0f + n2) / (norm + 1e-9f);
    out[g] = scale * sv;
}

// ---------------------------------------------------------------------------
template <int NP>
static void run_pipeline(const float* x, const float* w, float* outp,
                         void* d_ws, hipStream_t stream)
{
    float* sA    = (float*)d_ws;                       // NP*BKO  (s1, then s3)
    float* sB    = sA + (size_t)NP * BKO;              // NP*BKO  (s2)
    float* v1buf = sB + (size_t)NP * BKO;              // BKO
    unsigned short* u = (unsigned short*)(v1buf + BKO);

    uhat_kernel<<<dim3(72, 4, 5), 256, 0, stream>>>(x, w, u);
    // pass 1 (uniform c = 1/K) -> s1 in sA
    route_uniform<NP><<<dim3(NP, 256), 256, 0, stream>>>(u, sA);
    // pass 2: prologue v1 = squash(sum sA), persist v1; out s2 -> sB
    route_pass<NP, 0, 1><<<dim3(NP, 256), 256, 0, stream>>>(u, sA, v1buf, sB);
    // pass 3: prologue v12 = squash(sum sB) + v1; out s3 -> sA (reuse)
    route_pass<NP, 1, 0><<<dim3(NP, 256), 256, 0, stream>>>(u, sB, v1buf, sA);
    squash_final<NP><<<160, 256, 0, stream>>>(sA, outp);
}

extern "C" void kernel_launch(void* const* d_in, const int* in_sizes, int n_in,
                              void* d_out, int out_size, void* d_ws, size_t ws_size,
                              hipStream_t stream)
{
    const float* x = (const float*)d_in[0];
    const float* w = (const float*)d_in[1];
    float* outp = (float*)d_out;

    const size_t ubytes = (size_t)B_ * K_ * I_ * O_ * 2;
    auto need = [&](int np) {
        return (size_t)(2 * np + 1) * BKO * 4 + ubytes;
    };
    if      (ws_size >= need(9)) run_pipeline<9>(x, w, outp, d_ws, stream);
    else if (ws_size >= need(6)) run_pipeline<6>(x, w, outp, d_ws, stream);
    else                         run_pipeline<3>(x, w, outp, d_ws, stream);
}